// Round 11
// baseline (355.138 us; speedup 1.0000x reference)
//
#include <hip/hip_runtime.h>

typedef float f32x4  __attribute__((ext_vector_type(4)));
typedef _Float16 f16x8  __attribute__((ext_vector_type(8)));
typedef _Float16 f16x4v __attribute__((ext_vector_type(4)));
typedef _Float16 f16x8v __attribute__((ext_vector_type(8)));

__device__ inline void load_lds16(const _Float16* g, _Float16* l) {
    __builtin_amdgcn_global_load_lds((const __attribute__((address_space(1))) void*)g,
                                     (__attribute__((address_space(3))) void*)l, 16, 0, 0);
}

// ---------------------------------------------------------------------------
// convert_h: fp32 -> fp16 (hi only; A-side operands need no lo term)
// ---------------------------------------------------------------------------
__global__ __launch_bounds__(256)
void convert_h(const float* __restrict__ X, _Float16* __restrict__ H, long n4)
{
    long i = (long)blockIdx.x * 256 + threadIdx.x;
    if (i >= n4) return;
    f32x4 v = ((const f32x4*)X)[i];
    f16x4v h;
#pragma unroll
    for (int k = 0; k < 4; ++k) h[k] = (_Float16)v[k];
    ((f16x4v*)H)[i] = h;
}

// ---------------------------------------------------------------------------
// transpose_w3: Wq,Wk -> W2 [2048][2048] fp16 stacked-K (k<1024 hi, k>=1024 lo)
//               Wv -> Wvt [1024][1024] fp16 hi. One dispatch, z = 0/1/2.
// ---------------------------------------------------------------------------
__global__ __launch_bounds__(256)
void transpose_w3(const float* __restrict__ Wq, const float* __restrict__ Wk,
                  const float* __restrict__ Wv,
                  _Float16* __restrict__ W2, _Float16* __restrict__ Wvt, int D)
{
    const int z = blockIdx.z;
    const float* W = (z == 0) ? Wq : (z == 1) ? Wk : Wv;

    __shared__ float t[32][33];
    const int tid = threadIdx.x;
    const int bx = blockIdx.x * 32, by = blockIdx.y * 32;
    const int c = tid & 31, r0 = tid >> 5;
#pragma unroll
    for (int r = r0; r < 32; r += 8)
        t[r][c] = W[(long)(by + r) * D + bx + c];
    __syncthreads();
#pragma unroll
    for (int r = r0; r < 32; r += 8) {
        float v = t[c][r];                       // = W[by+c][bx+r]
        _Float16 h = (_Float16)v;
        if (z < 2) {
            const long nrow = (long)z * D + bx + r;      // stacked Q|K rows
            W2[nrow * 2 * D + by + c]     = h;           // hi at k
            W2[nrow * 2 * D + D + by + c] = (_Float16)(v - (float)h);  // lo at k+D
        } else {
            Wvt[(long)(bx + r) * D + by + c] = h;
        }
    }
}

// Staging macros: 256-row K-slice (16 KB, fold-128) and 128-row slice
// (8 KB, fold-64); source k pre-permuted by the read-side XOR (rule 21).
#define STAGES_T(NTHR, NQ, gb, ld, base0, kbase, dst)                           \
    do {                                                                        \
        _Pragma("unroll")                                                       \
        for (int q_ = 0; q_ < (NQ); ++q_) {                                     \
            const int p_ = q_ * (NTHR) + tid;                                   \
            const int rp_ = p_ >> 3;                                            \
            const int gl_ = (p_ & 7) ^ (rp_ & 7);                               \
            const int row_ = rp_ + ((gl_ >> 2) << 7);                           \
            load_lds16((gb) + (long)((base0) + row_) * (ld) + (kbase) +         \
                           ((gl_ & 3) << 3),                                    \
                       (dst) + p_ * 8);                                         \
        }                                                                       \
    } while (0)

#define STAGEB128(gb, ld, base0, kbase, dst)                                    \
    do {                                                                        \
        _Pragma("unroll")                                                       \
        for (int q_ = 0; q_ < 2; ++q_) {                                        \
            const int p_ = q_ * 256 + tid;                                      \
            const int rp_ = p_ >> 3;                                            \
            const int gl_ = (p_ & 7) ^ (rp_ & 7);                               \
            const int row_ = rp_ + ((gl_ >> 2) << 6);                           \
            load_lds16((gb) + (long)((base0) + row_) * (ld) + (kbase) +         \
                           ((gl_ & 3) << 3),                                    \
                       (dst) + p_ * 8);                                         \
        }                                                                       \
    } while (0)

// ---------------------------------------------------------------------------
// projQK: Q and K projections only (V moved to sc_v). 256 blocks = one clean
// round on 256 CUs. 256x256 tiles, 8 waves 2M x 4N, ring-4 BK=32, single
// barrier + counted vmcnt(4) per step.
// ---------------------------------------------------------------------------
__global__ __launch_bounds__(512)
void projQK(const _Float16* __restrict__ x_h, const _Float16* __restrict__ W2,
            _Float16* __restrict__ Q_h, _Float16* __restrict__ Khl,
            const float* __restrict__ bq, const float* __restrict__ bk)
{
    constexpr int D = 1024;
    __shared__ __align__(16) _Float16 lds[65536];   // 128 KB

    const int orig = blockIdx.x;
    const int x = orig & 7, i = orig >> 3;
    const int rt = x * 4 + (i & 3), ct = i >> 2;    // rt [0,32), ct [0,8)
    const int row0 = rt * 256, col0 = ct * 256;
    constexpr int NT2 = 64;

    const int tid = threadIdx.x;
    const int wave = tid >> 6, lane = tid & 63, l16 = lane & 15, quad = lane >> 4;
    const int wmh = (wave >> 2) * 128;
    const int wn  = (wave & 3) * 64;
    const int ahalf = (wave >> 2) << 2;

    STAGES_T(512, 2, x_h, D, row0, 0,  lds);
    STAGES_T(512, 2, W2, 2048, col0, 0, lds + 32768);
    STAGES_T(512, 2, x_h, D, row0, 32, lds + 8192);
    STAGES_T(512, 2, W2, 2048, col0, 32, lds + 32768 + 8192);
    asm volatile("s_waitcnt vmcnt(4)" ::: "memory");
    __builtin_amdgcn_s_barrier();

    f32x4 acc[8][4] = {};

    for (int s = 0; s < NT2; ++s) {
        _Float16* Asl = lds + (s & 3) * 8192;
        _Float16* Bsl = lds + 32768 + (s & 3) * 8192;
        const bool pf = (s + 2 < NT2);
        const int kA2 = ((s + 2) * 32) & (D - 1);
        const int kB2 = (s + 2) * 32;

        f16x8 b[4], a0[4];
#pragma unroll
        for (int j = 0; j < 4; ++j) {
            const int nr = wn + j * 16 + l16;
            const int rpb = nr & 127;
            const int gpb = ((((nr >> 7) << 2) | quad) ^ (rpb & 7));
            b[j] = *(const f16x8*)&Bsl[rpb * 64 + gpb * 8];
        }
#pragma unroll
        for (int il = 0; il < 4; ++il) {
            const int rp = il * 16 + l16;
            const int gpa = ((ahalf | quad) ^ (rp & 7));
            a0[il] = *(const f16x8*)&Asl[rp * 64 + gpa * 8];
        }
        if (pf) STAGES_T(512, 2, x_h, D, row0, kA2, lds + ((s + 2) & 3) * 8192);
        __builtin_amdgcn_s_setprio(1);
#pragma unroll
        for (int il = 0; il < 4; ++il)
#pragma unroll
            for (int j = 0; j < 4; ++j)
                acc[il][j] = __builtin_amdgcn_mfma_f32_16x16x32_f16(
                    a0[il], b[j], acc[il][j], 0, 0, 0);
        __builtin_amdgcn_s_setprio(0);

        f16x8 a1[4];
#pragma unroll
        for (int il = 0; il < 4; ++il) {
            const int rp = (il + 4) * 16 + l16;
            const int gpa = ((ahalf | quad) ^ (rp & 7));
            a1[il] = *(const f16x8*)&Asl[rp * 64 + gpa * 8];
        }
        if (pf) STAGES_T(512, 2, W2, 2048, col0, kB2, lds + 32768 + ((s + 2) & 3) * 8192);
        __builtin_amdgcn_s_setprio(1);
#pragma unroll
        for (int il = 0; il < 4; ++il)
#pragma unroll
            for (int j = 0; j < 4; ++j)
                acc[4 + il][j] = __builtin_amdgcn_mfma_f32_16x16x32_f16(
                    a1[il], b[j], acc[4 + il][j], 0, 0, 0);
        __builtin_amdgcn_s_setprio(0);

        if (pf)                asm volatile("s_waitcnt vmcnt(4)" ::: "memory");
        else if (s + 2 == NT2) asm volatile("s_waitcnt vmcnt(0)" ::: "memory");
        __builtin_amdgcn_s_barrier();
    }

    const bool isQ = ct < 4;
    const float* bias = isQ ? bq : bk;
#pragma unroll
    for (int j = 0; j < 4; ++j) {
        const int colg = col0 + wn + j * 16 + l16;
        const int cc = isQ ? colg : colg - D;
        const float bval = bias[cc];
#pragma unroll
        for (int i = 0; i < 8; ++i) {
            const int rb = row0 + wmh + i * 16 + quad * 4;
#pragma unroll
            for (int r = 0; r < 4; ++r) {
                const float v = acc[i][j][r] + bval;
                const _Float16 h = (_Float16)v;
                if (isQ) {
                    Q_h[(long)(rb + r) * D + cc] = h;
                } else {
                    Khl[(long)(rb + r) * 2048 + cc] = h;
                    Khl[(long)(rb + r) * 2048 + 1024 + cc] = (_Float16)(v - (float)h);
                }
            }
        }
    }
}

// ---------------------------------------------------------------------------
// sc_v: scores (288 blocks) + V projection (256 blocks) in ONE dispatch.
// 256 threads / 4 waves (2M x 2N, wave tile 128x64), 48 KB ring-2 LDS ->
// 3 blocks/CU co-resident; V work fills the scores dispatch's slack.
//   blocks 0..287:  scores 256x128 causal tiles (72/batch), K'=2048
//                   (A = Q dup-K, B = Khl hi|lo), 64 steps.
//   blocks 288..543: V proj 256(s)x128(d) tiles, K=1024, 32 steps;
//                   chunked 2x32KB LDS-transpose epilogue -> Vt [B][D][S].
// ---------------------------------------------------------------------------
__global__ __launch_bounds__(256)
void sc_v(const _Float16* __restrict__ Q, const _Float16* __restrict__ Khl,
          float* __restrict__ Sc,
          const _Float16* __restrict__ x_h, const _Float16* __restrict__ Wvt,
          _Float16* __restrict__ Vt, const float* __restrict__ bv)
{
    constexpr int D = 1024, S = 2048;
    __shared__ __align__(16) _Float16 lds[24576];   // 48 KB

    const int bx = blockIdx.x;
    const bool isV = bx >= 288;

    const int tid = threadIdx.x;
    const int wave = tid >> 6, lane = tid & 63, l16 = lane & 15, quad = lane >> 4;
    const int wmh = (wave >> 1) * 128;
    const int wn  = (wave & 1) * 64;
    const int ahalf = (wave >> 1) << 2;

    const _Float16 *gA, *gB;
    int row0, col0, NT2, ldb, bz;
    if (!isV) {
        bz = bx / 72;
        const int t = bx % 72;
        int rt = (int)sqrtf((float)t);
        while (rt * (rt + 1) > t) --rt;
        while ((rt + 1) * (rt + 2) <= t) ++rt;
        const int ct = t - rt * (rt + 1);     // [0, 2rt+2)
        row0 = rt * 256; col0 = ct * 128;
        gA = Q + (long)bz * S * D;
        gB = Khl + (long)bz * S * 2048;
        NT2 = 64; ldb = 2048;
    } else {
        const int o = bx - 288;               // [0,256)
        const int rtg = o & 31, ctv = o >> 5; // rtg: global 256-row tile
        row0 = rtg * 256; col0 = ctv * 128;
        gA = x_h;  gB = Wvt;
        NT2 = 32; ldb = D;
        bz = 0;
    }

    STAGES_T(256, 4, gA, D, row0, 0, lds);
    STAGEB128(gB, ldb, col0, 0, lds + 16384);
    asm volatile("s_waitcnt vmcnt(0)" ::: "memory");
    __builtin_amdgcn_s_barrier();

    f32x4 acc[8][4] = {};

    for (int s = 0; s < NT2; ++s) {
        _Float16* Asl = lds + (s & 1) * 8192;
        _Float16* Bsl = lds + 16384 + (s & 1) * 4096;
        const bool pf = (s + 1 < NT2);
        const int kA = ((s + 1) * 32) & (D - 1);   // A dup-K (sc)
        const int kB = (s + 1) * 32;

        f16x8 b[4], a[8];
#pragma unroll
        for (int j = 0; j < 4; ++j) {
            const int nr = wn + j * 16 + l16;
            const int rpb = nr & 63;
            const int gpb = ((((nr >> 6) << 2) | quad) ^ (rpb & 7));
            b[j] = *(const f16x8*)&Bsl[rpb * 64 + gpb * 8];
        }
#pragma unroll
        for (int il = 0; il < 8; ++il) {
            const int rp = il * 16 + l16;
            const int gpa = ((ahalf | quad) ^ (rp & 7));
            a[il] = *(const f16x8*)&Asl[rp * 64 + gpa * 8];
        }
        if (pf) {
            STAGES_T(256, 4, gA, D, row0, kA, lds + ((s + 1) & 1) * 8192);
            STAGEB128(gB, ldb, col0, kB, lds + 16384 + ((s + 1) & 1) * 4096);
        }
        __builtin_amdgcn_s_setprio(1);
#pragma unroll
        for (int il = 0; il < 8; ++il)
#pragma unroll
            for (int j = 0; j < 4; ++j)
                acc[il][j] = __builtin_amdgcn_mfma_f32_16x16x32_f16(
                    a[il], b[j], acc[il][j], 0, 0, 0);
        __builtin_amdgcn_s_setprio(0);

        asm volatile("s_waitcnt vmcnt(0)" ::: "memory");
        __builtin_amdgcn_s_barrier();
    }

    if (!isV) {
        float* cf = Sc + (long)bz * S * S;
#pragma unroll
        for (int j = 0; j < 4; ++j) {
            const int col = col0 + wn + j * 16 + l16;
#pragma unroll
            for (int i = 0; i < 8; ++i) {
                const int rb = row0 + wmh + i * 16 + quad * 4;
#pragma unroll
                for (int r = 0; r < 4; ++r)
                    cf[(long)(rb + r) * S + col] = acc[i][j][r];
            }
        }
    } else {
        // chunked transpose epilogue: 2 chunks of 64 cols (32 KB each)
        _Float16* sVt = lds;
        const int bb = row0 >> 11;           // tiles never cross batches
        const int s0 = row0 & (S - 1);
#pragma unroll
        for (int ch = 0; ch < 2; ++ch) {
            if ((wave & 1) == ch) {          // the 2 waves owning these cols
#pragma unroll
                for (int j = 0; j < 4; ++j) {
                    const int cl2 = j * 16 + l16;          // [0,64)
                    const float bval = bv[col0 + ch * 64 + cl2];
#pragma unroll
                    for (int i = 0; i < 8; ++i) {
                        f16x4v pk;
#pragma unroll
                        for (int r = 0; r < 4; ++r)
                            pk[r] = (_Float16)(acc[i][j][r] + bval);
                        const int rowb = wmh * 2 + i * 32 + quad * 8;
                        const int sb = cl2 * 512 + (rowb ^ ((cl2 & 31) << 4));
                        *(f16x4v*)((char*)sVt + sb) = pk;
                    }
                }
            }
            __syncthreads();
            for (int idx = tid; idx < 2048; idx += 256) {
                const int cl2 = idx >> 5, r8 = idx & 31;
                const int sb = cl2 * 512 + ((r8 * 16) ^ ((cl2 & 31) << 4));
                f16x8v v = *(const f16x8v*)((char*)sVt + sb);
                *(f16x8v*)&Vt[((long)bb * D + col0 + ch * 64 + cl2) * S +
                              s0 + r8 * 8] = v;
            }
            __syncthreads();
        }
    }
}

// ---------------------------------------------------------------------------
// gemm_pv: out = P @ Vt^T-layout. 256x128 tiles, 4 waves (2M x 2N), ring-2
// 48 KB -> 3 blocks/CU; heavy rows first so light tiles fill the tail.
// ---------------------------------------------------------------------------
__global__ __launch_bounds__(256)
void gemm_pv(const _Float16* __restrict__ P, const _Float16* __restrict__ Vt,
             float* __restrict__ Out)
{
    constexpr int D = 1024, S = 2048;
    __shared__ __align__(16) _Float16 lds[24576];   // 48 KB

    const int rt = 7 - (int)blockIdx.x;   // heavy rows first
    const int ct = blockIdx.y;
    const int bz = blockIdx.z;
    const _Float16* gA = P + (long)bz * S * S;
    const _Float16* gB = Vt + (long)bz * D * S;
    const int row0 = rt * 256, col0 = ct * 128;
    const int NT2 = (rt + 1) * 8;

    const int tid = threadIdx.x;
    const int wave = tid >> 6, lane = tid & 63, l16 = lane & 15, quad = lane >> 4;
    const int wmh = (wave >> 1) * 128;
    const int wn  = (wave & 1) * 64;
    const int ahalf = (wave >> 1) << 2;

    STAGES_T(256, 4, gA, S, row0, 0, lds);
    STAGEB128(gB, S, col0, 0, lds + 16384);
    asm volatile("s_waitcnt vmcnt(0)" ::: "memory");
    __builtin_amdgcn_s_barrier();

    f32x4 acc[8][4] = {};

    for (int s = 0; s < NT2; ++s) {
        _Float16* Asl = lds + (s & 1) * 8192;
        _Float16* Bsl = lds + 16384 + (s & 1) * 4096;
        const bool pf = (s + 1 < NT2);
        const int k1 = (s + 1) * 32;

        f16x8 b[4], a[8];
#pragma unroll
        for (int j = 0; j < 4; ++j) {
            const int nr = wn + j * 16 + l16;
            const int rpb = nr & 63;
            const int gpb = ((((nr >> 6) << 2) | quad) ^ (rpb & 7));
            b[j] = *(const f16x8*)&Bsl[rpb * 64 + gpb * 8];
        }
#pragma unroll
        for (int il = 0; il < 8; ++il) {
            const int rp = il * 16 + l16;
            const int gpa = ((ahalf | quad) ^ (rp & 7));
            a[il] = *(const f16x8*)&Asl[rp * 64 + gpa * 8];
        }
        if (pf) {
            STAGES_T(256, 4, gA, S, row0, k1, lds + ((s + 1) & 1) * 8192);
            STAGEB128(gB, S, col0, k1, lds + 16384 + ((s + 1) & 1) * 4096);
        }
        __builtin_amdgcn_s_setprio(1);
#pragma unroll
        for (int il = 0; il < 8; ++il)
#pragma unroll
            for (int j = 0; j < 4; ++j)
                acc[il][j] = __builtin_amdgcn_mfma_f32_16x16x32_f16(
                    a[il], b[j], acc[il][j], 0, 0, 0);
        __builtin_amdgcn_s_setprio(0);

        asm volatile("s_waitcnt vmcnt(0)" ::: "memory");
        __builtin_amdgcn_s_barrier();
    }

    float* cf = Out + (long)bz * S * D;
#pragma unroll
    for (int j = 0; j < 4; ++j) {
        const int col = col0 + wn + j * 16 + l16;
#pragma unroll
        for (int i = 0; i < 8; ++i) {
            const int rb = row0 + wmh + i * 16 + quad * 4;
#pragma unroll
            for (int r = 0; r < 4; ++r)
                cf[(long)(rb + r) * D + col] = acc[i][j][r];
        }
    }
}

// ---------------------------------------------------------------------------
// softmax: causal, fp32 Sc row -> fp16 P row; writes the 256-aligned live
// region gemm_pv will read (dead columns get zeros).
// ---------------------------------------------------------------------------
__global__ __launch_bounds__(256)
void softmax_kernel(const float* __restrict__ Sc, _Float16* __restrict__ P, int seq)
{
    const int r = blockIdx.x, b = blockIdx.y;
    const float* row = Sc + ((long)b * seq + r) * seq;
    _Float16* prow = P + ((long)b * seq + r) * seq;
    const int tid = threadIdx.x;
    const int cmax = ((r >> 8) + 1) << 8;
    const int c0 = tid * 8;

    float v[8];
    f32x4 v0, v1;
    if (c0 <= r) {
        const f32x4* rp = (const f32x4*)row;
        v0 = rp[tid * 2];
        v1 = rp[tid * 2 + 1];
    } else {
        v0 = (f32x4)(-3.0e38f);
        v1 = (f32x4)(-3.0e38f);
    }
    float lmax = -3.0e38f;
#pragma unroll
    for (int k = 0; k < 4; ++k) {
        v[k]     = (c0 + k     <= r) ? v0[k] : -3.0e38f;
        v[k + 4] = (c0 + k + 4 <= r) ? v1[k] : -3.0e38f;
    }
#pragma unroll
    for (int k = 0; k < 8; ++k) lmax = fmaxf(lmax, v[k]);

    __shared__ float red[256];
    red[tid] = lmax; __syncthreads();
    for (int s = 128; s > 0; s >>= 1) {
        if (tid < s) red[tid] = fmaxf(red[tid], red[tid + s]);
        __syncthreads();
    }
    const float m = red[0];
    __syncthreads();

    float lsum = 0.0f;
#pragma unroll
    for (int k = 0; k < 8; ++k) {
        float e = (v[k] > -1.0e38f) ? __expf(v[k] - m) : 0.0f;
        v[k] = e;
        lsum += e;
    }
    red[tid] = lsum; __syncthreads();
    for (int s = 128; s > 0; s >>= 1) {
        if (tid < s) red[tid] += red[tid + s];
        __syncthreads();
    }
    const float inv = 1.0f / red[0];

    if (c0 < cmax) {
        f16x8v o;
#pragma unroll
        for (int k = 0; k < 8; ++k) o[k] = (_Float16)(v[k] * inv);
        ((f16x8v*)prow)[tid] = o;
    }
}

// ---------------------------------------------------------------------------
// layout: x_h[0,16) Wvt[16,18) Q_h[18,34) Khl[34,66) Vt[66,82) Sc[82,146)
//         W2[146,154). P[0,32) overlaps x_h/Wvt/Q_h, which are dead once
//         sc_v finishes (softmax writes P reading only Sc; gemm_pv reads
//         P + Vt). All phase-wise disjoint.
// ---------------------------------------------------------------------------
extern "C" void kernel_launch(void* const* d_in, const int* in_sizes, int n_in,
                              void* d_out, int out_size, void* d_ws, size_t ws_size,
                              hipStream_t stream)
{
    constexpr int B = 4, S = 2048, D = 1024;
    constexpr long MB = 1024 * 1024;
    const float* x  = (const float*)d_in[0];
    const float* Wq = (const float*)d_in[1];
    const float* bq = (const float*)d_in[2];
    const float* Wk = (const float*)d_in[3];
    const float* bk = (const float*)d_in[4];
    const float* Wv = (const float*)d_in[5];
    const float* bv = (const float*)d_in[6];
    float* out = (float*)d_out;

    char* ws = (char*)d_ws;
    _Float16* x_h = (_Float16*)(ws + 0);           // [0,16)
    _Float16* Wvt = (_Float16*)(ws + 16 * MB);     // [16,18)
    _Float16* Q_h = (_Float16*)(ws + 18 * MB);     // [18,34)
    _Float16* Khl = (_Float16*)(ws + 34 * MB);     // [34,66)
    _Float16* Vt  = (_Float16*)(ws + 66 * MB);     // [66,82)
    float*    Sc  = (float*)(ws + 82 * MB);        // [82,146)
    _Float16* W2  = (_Float16*)(ws + 146 * MB);    // [146,154)
    _Float16* P   = (_Float16*)(ws + 0);           // [0,32) after x_h/Wvt/Q_h die

    const int M = B * S;
    dim3 blk(256);

    convert_h<<<(M * D / 4 + 255) / 256, blk, 0, stream>>>(x, x_h, (long)M * D / 4);
    transpose_w3<<<dim3(D / 32, D / 32, 3), blk, 0, stream>>>(Wq, Wk, Wv, W2, Wvt, D);
    projQK<<<dim3(256), dim3(512), 0, stream>>>(x_h, W2, Q_h, Khl, bq, bk);
    sc_v<<<dim3(544), blk, 0, stream>>>(Q_h, Khl, Sc, x_h, Wvt, Vt, bv);
    softmax_kernel<<<dim3(S, B), blk, 0, stream>>>(Sc, P, S);
    gemm_pv<<<dim3(8, 8, B), blk, 0, stream>>>(P, Vt, out);
}

// Round 12
// 311.911 us; speedup vs baseline: 1.1386x; 1.1386x over previous
//
#include <hip/hip_runtime.h>

typedef float f32x4  __attribute__((ext_vector_type(4)));
typedef _Float16 f16x8  __attribute__((ext_vector_type(8)));
typedef _Float16 f16x4v __attribute__((ext_vector_type(4)));
typedef _Float16 f16x8v __attribute__((ext_vector_type(8)));

__device__ inline void load_lds16(const _Float16* g, _Float16* l) {
    __builtin_amdgcn_global_load_lds((const __attribute__((address_space(1))) void*)g,
                                     (__attribute__((address_space(3))) void*)l, 16, 0, 0);
}

// ---------------------------------------------------------------------------
// convert_h: fp32 -> fp16 (hi only; A-side operands need no lo term)
// ---------------------------------------------------------------------------
__global__ __launch_bounds__(256)
void convert_h(const float* __restrict__ X, _Float16* __restrict__ H, long n4)
{
    long i = (long)blockIdx.x * 256 + threadIdx.x;
    if (i >= n4) return;
    f32x4 v = ((const f32x4*)X)[i];
    f16x4v h;
#pragma unroll
    for (int k = 0; k < 4; ++k) h[k] = (_Float16)v[k];
    ((f16x4v*)H)[i] = h;
}

// ---------------------------------------------------------------------------
// transpose_w3: Wq,Wk -> W2 [2048][2048] fp16 stacked-K (k<1024 hi, k>=1024 lo)
//               Wv -> Wvt [1024][1024] fp16 hi. One dispatch, z = 0/1/2.
// ---------------------------------------------------------------------------
__global__ __launch_bounds__(256)
void transpose_w3(const float* __restrict__ Wq, const float* __restrict__ Wk,
                  const float* __restrict__ Wv,
                  _Float16* __restrict__ W2, _Float16* __restrict__ Wvt, int D)
{
    const int z = blockIdx.z;
    const float* W = (z == 0) ? Wq : (z == 1) ? Wk : Wv;

    __shared__ float t[32][33];
    const int tid = threadIdx.x;
    const int bx = blockIdx.x * 32, by = blockIdx.y * 32;
    const int c = tid & 31, r0 = tid >> 5;
#pragma unroll
    for (int r = r0; r < 32; r += 8)
        t[r][c] = W[(long)(by + r) * D + bx + c];
    __syncthreads();
#pragma unroll
    for (int r = r0; r < 32; r += 8) {
        float v = t[c][r];                       // = W[by+c][bx+r]
        _Float16 h = (_Float16)v;
        if (z < 2) {
            const long nrow = (long)z * D + bx + r;      // stacked Q|K rows
            W2[nrow * 2 * D + by + c]     = h;           // hi at k
            W2[nrow * 2 * D + D + by + c] = (_Float16)(v - (float)h);  // lo at k+D
        } else {
            Wvt[(long)(bx + r) * D + by + c] = h;
        }
    }
}

// Staging macros: 256-row K-slice (16 KB, fold-128) and 128-row slice
// (8 KB, fold-64); source k pre-permuted by the read-side XOR (rule 21).
#define STAGES_T(NTHR, NQ, gb, ld, base0, kbase, dst)                           \
    do {                                                                        \
        _Pragma("unroll")                                                       \
        for (int q_ = 0; q_ < (NQ); ++q_) {                                     \
            const int p_ = q_ * (NTHR) + tid;                                   \
            const int rp_ = p_ >> 3;                                            \
            const int gl_ = (p_ & 7) ^ (rp_ & 7);                               \
            const int row_ = rp_ + ((gl_ >> 2) << 7);                           \
            load_lds16((gb) + (long)((base0) + row_) * (ld) + (kbase) +         \
                           ((gl_ & 3) << 3),                                    \
                       (dst) + p_ * 8);                                         \
        }                                                                       \
    } while (0)

#define STAGEB128(gb, ld, base0, kbase, dst)                                    \
    do {                                                                        \
        _Pragma("unroll")                                                       \
        for (int q_ = 0; q_ < 2; ++q_) {                                        \
            const int p_ = q_ * 256 + tid;                                      \
            const int rp_ = p_ >> 3;                                            \
            const int gl_ = (p_ & 7) ^ (rp_ & 7);                               \
            const int row_ = rp_ + ((gl_ >> 2) << 6);                           \
            load_lds16((gb) + (long)((base0) + row_) * (ld) + (kbase) +         \
                           ((gl_ & 3) << 3),                                    \
                       (dst) + p_ * 8);                                         \
        }                                                                       \
    } while (0)

// ---------------------------------------------------------------------------
// projQK: Q and K projections only. 256 equal blocks = one clean round on
// 256 CUs (R9 tail analysis: the old combined grid's V half-round ran on
// half the machine). 256x256 tiles, 8 waves 2M x 4N, ring-4 BK=32, single
// barrier + counted vmcnt(4) per step. [verified correct in R11 run]
// ---------------------------------------------------------------------------
__global__ __launch_bounds__(512)
void projQK(const _Float16* __restrict__ x_h, const _Float16* __restrict__ W2,
            _Float16* __restrict__ Q_h, _Float16* __restrict__ Khl,
            const float* __restrict__ bq, const float* __restrict__ bk)
{
    constexpr int D = 1024;
    __shared__ __align__(16) _Float16 lds[65536];   // 128 KB

    const int orig = blockIdx.x;
    const int x = orig & 7, i = orig >> 3;
    const int rt = x * 4 + (i & 3), ct = i >> 2;    // rt [0,32), ct [0,8)
    const int row0 = rt * 256, col0 = ct * 256;
    constexpr int NT2 = 64;

    const int tid = threadIdx.x;
    const int wave = tid >> 6, lane = tid & 63, l16 = lane & 15, quad = lane >> 4;
    const int wmh = (wave >> 2) * 128;
    const int wn  = (wave & 3) * 64;
    const int ahalf = (wave >> 2) << 2;

    STAGES_T(512, 2, x_h, D, row0, 0,  lds);
    STAGES_T(512, 2, W2, 2048, col0, 0, lds + 32768);
    STAGES_T(512, 2, x_h, D, row0, 32, lds + 8192);
    STAGES_T(512, 2, W2, 2048, col0, 32, lds + 32768 + 8192);
    asm volatile("s_waitcnt vmcnt(4)" ::: "memory");
    __builtin_amdgcn_s_barrier();

    f32x4 acc[8][4] = {};

    for (int s = 0; s < NT2; ++s) {
        _Float16* Asl = lds + (s & 3) * 8192;
        _Float16* Bsl = lds + 32768 + (s & 3) * 8192;
        const bool pf = (s + 2 < NT2);
        const int kA2 = ((s + 2) * 32) & (D - 1);
        const int kB2 = (s + 2) * 32;

        f16x8 b[4], a0[4];
#pragma unroll
        for (int j = 0; j < 4; ++j) {
            const int nr = wn + j * 16 + l16;
            const int rpb = nr & 127;
            const int gpb = ((((nr >> 7) << 2) | quad) ^ (rpb & 7));
            b[j] = *(const f16x8*)&Bsl[rpb * 64 + gpb * 8];
        }
#pragma unroll
        for (int il = 0; il < 4; ++il) {
            const int rp = il * 16 + l16;
            const int gpa = ((ahalf | quad) ^ (rp & 7));
            a0[il] = *(const f16x8*)&Asl[rp * 64 + gpa * 8];
        }
        if (pf) STAGES_T(512, 2, x_h, D, row0, kA2, lds + ((s + 2) & 3) * 8192);
        __builtin_amdgcn_s_setprio(1);
#pragma unroll
        for (int il = 0; il < 4; ++il)
#pragma unroll
            for (int j = 0; j < 4; ++j)
                acc[il][j] = __builtin_amdgcn_mfma_f32_16x16x32_f16(
                    a0[il], b[j], acc[il][j], 0, 0, 0);
        __builtin_amdgcn_s_setprio(0);

        f16x8 a1[4];
#pragma unroll
        for (int il = 0; il < 4; ++il) {
            const int rp = (il + 4) * 16 + l16;
            const int gpa = ((ahalf | quad) ^ (rp & 7));
            a1[il] = *(const f16x8*)&Asl[rp * 64 + gpa * 8];
        }
        if (pf) STAGES_T(512, 2, W2, 2048, col0, kB2, lds + 32768 + ((s + 2) & 3) * 8192);
        __builtin_amdgcn_s_setprio(1);
#pragma unroll
        for (int il = 0; il < 4; ++il)
#pragma unroll
            for (int j = 0; j < 4; ++j)
                acc[4 + il][j] = __builtin_amdgcn_mfma_f32_16x16x32_f16(
                    a1[il], b[j], acc[4 + il][j], 0, 0, 0);
        __builtin_amdgcn_s_setprio(0);

        if (pf)                asm volatile("s_waitcnt vmcnt(4)" ::: "memory");
        else if (s + 2 == NT2) asm volatile("s_waitcnt vmcnt(0)" ::: "memory");
        __builtin_amdgcn_s_barrier();
    }

    const bool isQ = ct < 4;
    const float* bias = isQ ? bq : bk;
#pragma unroll
    for (int j = 0; j < 4; ++j) {
        const int colg = col0 + wn + j * 16 + l16;
        const int cc = isQ ? colg : colg - D;
        const float bval = bias[cc];
#pragma unroll
        for (int i = 0; i < 8; ++i) {
            const int rb = row0 + wmh + i * 16 + quad * 4;
#pragma unroll
            for (int r = 0; r < 4; ++r) {
                const float v = acc[i][j][r] + bval;
                const _Float16 h = (_Float16)v;
                if (isQ) {
                    Q_h[(long)(rb + r) * D + cc] = h;
                } else {
                    Khl[(long)(rb + r) * 2048 + cc] = h;
                    Khl[(long)(rb + r) * 2048 + 1024 + cc] = (_Float16)(v - (float)h);
                }
            }
        }
    }
}

// ---------------------------------------------------------------------------
// projV: V projection, 256 blocks (one round), 256 threads / 4 waves
// (2M x 2N, wave 128x64), tile 256(s-rows) x 128(d-cols), NT2=32, ring-4
// 96 KB, counted vmcnt(6) (R6 gemm_pv loop, verified) + chunked 2x32KB
// LDS-transpose epilogue -> Vt [B][D][S] (R11 sc_v V-branch, verified).
// ---------------------------------------------------------------------------
__global__ __launch_bounds__(256)
void projV(const _Float16* __restrict__ x_h, const _Float16* __restrict__ Wvt,
           _Float16* __restrict__ Vt, const float* __restrict__ bv)
{
    constexpr int D = 1024, S = 2048;
    __shared__ __align__(16) _Float16 lds[49152];   // 96 KB: A 4x16KB, B 4x8KB

    const int o = blockIdx.x;                 // [0,256)
    const int rtg = o & 31, ctv = o >> 5;     // 256-row s-tile, 128-col d-tile
    const int row0 = rtg * 256, col0 = ctv * 128;
    constexpr int NT2 = 32;

    const int tid = threadIdx.x;
    const int wave = tid >> 6, lane = tid & 63, l16 = lane & 15, quad = lane >> 4;
    const int wmh = (wave >> 1) * 128;
    const int wn  = (wave & 1) * 64;
    const int ahalf = (wave >> 1) << 2;

    STAGES_T(256, 4, x_h, D, row0, 0,  lds);
    STAGEB128(Wvt, D, col0, 0, lds + 32768);
    STAGES_T(256, 4, x_h, D, row0, 32, lds + 8192);
    STAGEB128(Wvt, D, col0, 32, lds + 32768 + 4096);
    asm volatile("s_waitcnt vmcnt(6)" ::: "memory");
    __builtin_amdgcn_s_barrier();

    f32x4 acc[8][4] = {};

    for (int s = 0; s < NT2; ++s) {
        _Float16* Asl = lds + (s & 3) * 8192;
        _Float16* Bsl = lds + 32768 + (s & 3) * 4096;
        const bool pf = (s + 2 < NT2);
        const int k2 = (s + 2) * 32;

        f16x8 b[4], a[8];
#pragma unroll
        for (int j = 0; j < 4; ++j) {
            const int nr = wn + j * 16 + l16;
            const int rpb = nr & 63;
            const int gpb = ((((nr >> 6) << 2) | quad) ^ (rpb & 7));
            b[j] = *(const f16x8*)&Bsl[rpb * 64 + gpb * 8];
        }
#pragma unroll
        for (int il = 0; il < 8; ++il) {
            const int rp = il * 16 + l16;
            const int gpa = ((ahalf | quad) ^ (rp & 7));
            a[il] = *(const f16x8*)&Asl[rp * 64 + gpa * 8];
        }
        if (pf) {
            STAGES_T(256, 4, x_h, D, row0, k2, lds + ((s + 2) & 3) * 8192);
            STAGEB128(Wvt, D, col0, k2, lds + 32768 + ((s + 2) & 3) * 4096);
        }
        __builtin_amdgcn_s_setprio(1);
#pragma unroll
        for (int il = 0; il < 8; ++il)
#pragma unroll
            for (int j = 0; j < 4; ++j)
                acc[il][j] = __builtin_amdgcn_mfma_f32_16x16x32_f16(
                    a[il], b[j], acc[il][j], 0, 0, 0);
        __builtin_amdgcn_s_setprio(0);

        if (pf)                asm volatile("s_waitcnt vmcnt(6)" ::: "memory");
        else if (s + 2 == NT2) asm volatile("s_waitcnt vmcnt(0)" ::: "memory");
        __builtin_amdgcn_s_barrier();
    }

    // chunked transpose epilogue: 2 chunks of 64 cols (32 KB each)
    _Float16* sVt = lds;
    const int bb = row0 >> 11;           // tiles never cross batches
    const int s0 = row0 & (S - 1);
    __syncthreads();
#pragma unroll
    for (int ch = 0; ch < 2; ++ch) {
        if ((wave & 1) == ch) {          // the 2 waves owning these cols
#pragma unroll
            for (int j = 0; j < 4; ++j) {
                const int cl2 = j * 16 + l16;          // [0,64)
                const float bval = bv[col0 + ch * 64 + cl2];
#pragma unroll
                for (int i = 0; i < 8; ++i) {
                    f16x4v pk;
#pragma unroll
                    for (int r = 0; r < 4; ++r)
                        pk[r] = (_Float16)(acc[i][j][r] + bval);
                    const int rowb = wmh * 2 + i * 32 + quad * 8;
                    const int sb = cl2 * 512 + (rowb ^ ((cl2 & 31) << 4));
                    *(f16x4v*)((char*)sVt + sb) = pk;
                }
            }
        }
        __syncthreads();
        for (int idx = tid; idx < 2048; idx += 256) {
            const int cl2 = idx >> 5, r8 = idx & 31;
            const int sb = cl2 * 512 + ((r8 * 16) ^ ((cl2 & 31) << 4));
            f16x8v v = *(const f16x8v*)((char*)sVt + sb);
            *(f16x8v*)&Vt[((long)bb * D + col0 + ch * 64 + cl2) * S +
                          s0 + r8 * 8] = v;
        }
        __syncthreads();
    }
}

// ---------------------------------------------------------------------------
// gemm_sc: scores = Q @ (Khl)^T, 2-term via stacked K' = 2048 (A = Q dup-K).
// 256x256 tiles, causal-packed triangular grid: 36/batch, 64 steps each.
// Ring-4 BK=32, single barrier + counted vmcnt(4). [R6-verified]
// ---------------------------------------------------------------------------
__global__ __launch_bounds__(512)
void gemm_sc(const _Float16* __restrict__ Q, const _Float16* __restrict__ Khl,
             float* __restrict__ Sc)
{
    constexpr int D = 1024, S = 2048;
    __shared__ __align__(16) _Float16 lds[65536];   // 128 KB

    const int bz = blockIdx.y;
    const int t = blockIdx.x;
    int rt = (int)((sqrtf(8.0f * t + 1.0f) - 1.0f) * 0.5f);
    while (rt * (rt + 1) / 2 > t) --rt;
    while ((rt + 1) * (rt + 2) / 2 <= t) ++rt;
    const int ct = t - rt * (rt + 1) / 2;

    const _Float16* gA = Q + (long)bz * S * D;
    const _Float16* gB = Khl + (long)bz * S * 2048;
    const int row0 = rt * 256, col0 = ct * 256;
    constexpr int NT2 = 64;

    const int tid = threadIdx.x;
    const int wave = tid >> 6, lane = tid & 63, l16 = lane & 15, quad = lane >> 4;
    const int wmh = (wave >> 2) * 128;
    const int wn  = (wave & 3) * 64;
    const int ahalf = (wave >> 2) << 2;

    STAGES_T(512, 2, gA, D, row0, 0,  lds);
    STAGES_T(512, 2, gB, 2048, col0, 0, lds + 32768);
    STAGES_T(512, 2, gA, D, row0, 32, lds + 8192);
    STAGES_T(512, 2, gB, 2048, col0, 32, lds + 32768 + 8192);
    asm volatile("s_waitcnt vmcnt(4)" ::: "memory");
    __builtin_amdgcn_s_barrier();

    f32x4 acc[8][4] = {};

    for (int s = 0; s < NT2; ++s) {
        _Float16* Asl = lds + (s & 3) * 8192;
        _Float16* Bsl = lds + 32768 + (s & 3) * 8192;
        const bool pf = (s + 2 < NT2);
        const int kA2 = ((s + 2) * 32) & (D - 1);
        const int kB2 = (s + 2) * 32;

        f16x8 b[4], a0[4];
#pragma unroll
        for (int j = 0; j < 4; ++j) {
            const int nr = wn + j * 16 + l16;
            const int rpb = nr & 127;
            const int gpb = ((((nr >> 7) << 2) | quad) ^ (rpb & 7));
            b[j] = *(const f16x8*)&Bsl[rpb * 64 + gpb * 8];
        }
#pragma unroll
        for (int il = 0; il < 4; ++il) {
            const int rp = il * 16 + l16;
            const int gpa = ((ahalf | quad) ^ (rp & 7));
            a0[il] = *(const f16x8*)&Asl[rp * 64 + gpa * 8];
        }
        if (pf) STAGES_T(512, 2, gA, D, row0, kA2, lds + ((s + 2) & 3) * 8192);
        __builtin_amdgcn_s_setprio(1);
#pragma unroll
        for (int il = 0; il < 4; ++il)
#pragma unroll
            for (int j = 0; j < 4; ++j)
                acc[il][j] = __builtin_amdgcn_mfma_f32_16x16x32_f16(
                    a0[il], b[j], acc[il][j], 0, 0, 0);
        __builtin_amdgcn_s_setprio(0);

        f16x8 a1[4];
#pragma unroll
        for (int il = 0; il < 4; ++il) {
            const int rp = (il + 4) * 16 + l16;
            const int gpa = ((ahalf | quad) ^ (rp & 7));
            a1[il] = *(const f16x8*)&Asl[rp * 64 + gpa * 8];
        }
        if (pf) STAGES_T(512, 2, gB, 2048, col0, kB2, lds + 32768 + ((s + 2) & 3) * 8192);
        __builtin_amdgcn_s_setprio(1);
#pragma unroll
        for (int il = 0; il < 4; ++il)
#pragma unroll
            for (int j = 0; j < 4; ++j)
                acc[4 + il][j] = __builtin_amdgcn_mfma_f32_16x16x32_f16(
                    a1[il], b[j], acc[4 + il][j], 0, 0, 0);
        __builtin_amdgcn_s_setprio(0);

        if (pf)                asm volatile("s_waitcnt vmcnt(4)" ::: "memory");
        else if (s + 2 == NT2) asm volatile("s_waitcnt vmcnt(0)" ::: "memory");
        __builtin_amdgcn_s_barrier();
    }

    float* cf = Sc + (long)bz * S * S;
#pragma unroll
    for (int j = 0; j < 4; ++j) {
        const int col = col0 + wn + j * 16 + l16;
#pragma unroll
        for (int i = 0; i < 8; ++i) {
            const int rb = row0 + wmh + i * 16 + quad * 4;
#pragma unroll
            for (int r = 0; r < 4; ++r)
                cf[(long)(rb + r) * S + col] = acc[i][j][r];
        }
    }
}

// ---------------------------------------------------------------------------
// gemm_pv: out = P @ Vt^T-layout. 256x128 tiles, 4 waves (2M x 2N), ring-4
// 96 KB, counted vmcnt(6), K bounded at (rt+1)*256, heavy rows first.
// [R6-verified]
// ---------------------------------------------------------------------------
__global__ __launch_bounds__(256)
void gemm_pv(const _Float16* __restrict__ P, const _Float16* __restrict__ Vt,
             float* __restrict__ Out)
{
    constexpr int D = 1024, S = 2048;
    __shared__ __align__(16) _Float16 lds[49152];   // 96 KB

    const int rt = 7 - (int)blockIdx.x;   // heavy rows first
    const int ct = blockIdx.y;
    const int bz = blockIdx.z;
    const _Float16* gA = P + (long)bz * S * S;
    const _Float16* gB = Vt + (long)bz * D * S;
    const int row0 = rt * 256, col0 = ct * 128;
    const int NT2 = (rt + 1) * 8;

    const int tid = threadIdx.x;
    const int wave = tid >> 6, lane = tid & 63, l16 = lane & 15, quad = lane >> 4;
    const int wmh = (wave >> 1) * 128;
    const int wn  = (wave & 1) * 64;
    const int ahalf = (wave >> 1) << 2;

    STAGES_T(256, 4, gA, S, row0, 0,  lds);
    STAGEB128(gB, S, col0, 0, lds + 32768);
    STAGES_T(256, 4, gA, S, row0, 32, lds + 8192);
    STAGEB128(gB, S, col0, 32, lds + 32768 + 4096);
    asm volatile("s_waitcnt vmcnt(6)" ::: "memory");
    __builtin_amdgcn_s_barrier();

    f32x4 acc[8][4] = {};

    for (int s = 0; s < NT2; ++s) {
        _Float16* Asl = lds + (s & 3) * 8192;
        _Float16* Bsl = lds + 32768 + (s & 3) * 4096;
        const bool pf = (s + 2 < NT2);
        const int k2 = (s + 2) * 32;

        f16x8 b[4], a[8];
#pragma unroll
        for (int j = 0; j < 4; ++j) {
            const int nr = wn + j * 16 + l16;
            const int rpb = nr & 63;
            const int gpb = ((((nr >> 6) << 2) | quad) ^ (rpb & 7));
            b[j] = *(const f16x8*)&Bsl[rpb * 64 + gpb * 8];
        }
#pragma unroll
        for (int il = 0; il < 8; ++il) {
            const int rp = il * 16 + l16;
            const int gpa = ((ahalf | quad) ^ (rp & 7));
            a[il] = *(const f16x8*)&Asl[rp * 64 + gpa * 8];
        }
        if (pf) {
            STAGES_T(256, 4, gA, S, row0, k2, lds + ((s + 2) & 3) * 8192);
            STAGEB128(gB, S, col0, k2, lds + 32768 + ((s + 2) & 3) * 4096);
        }
        __builtin_amdgcn_s_setprio(1);
#pragma unroll
        for (int il = 0; il < 8; ++il)
#pragma unroll
            for (int j = 0; j < 4; ++j)
                acc[il][j] = __builtin_amdgcn_mfma_f32_16x16x32_f16(
                    a[il], b[j], acc[il][j], 0, 0, 0);
        __builtin_amdgcn_s_setprio(0);

        if (pf)                asm volatile("s_waitcnt vmcnt(6)" ::: "memory");
        else if (s + 2 == NT2) asm volatile("s_waitcnt vmcnt(0)" ::: "memory");
        __builtin_amdgcn_s_barrier();
    }

    float* cf = Out + (long)bz * S * D;
#pragma unroll
    for (int j = 0; j < 4; ++j) {
        const int col = col0 + wn + j * 16 + l16;
#pragma unroll
        for (int i = 0; i < 8; ++i) {
            const int rb = row0 + wmh + i * 16 + quad * 4;
#pragma unroll
            for (int r = 0; r < 4; ++r)
                cf[(long)(rb + r) * D + col] = acc[i][j][r];
        }
    }
}

// ---------------------------------------------------------------------------
// softmax: causal, fp32 Sc row -> fp16 P row; writes the 256-aligned live
// region gemm_pv will read (dead columns get zeros). [R6-verified]
// ---------------------------------------------------------------------------
__global__ __launch_bounds__(256)
void softmax_kernel(const float* __restrict__ Sc, _Float16* __restrict__ P, int seq)
{
    const int r = blockIdx.x, b = blockIdx.y;
    const float* row = Sc + ((long)b * seq + r) * seq;
    _Float16* prow = P + ((long)b * seq + r) * seq;
    const int tid = threadIdx.x;
    const int cmax = ((r >> 8) + 1) << 8;
    const int c0 = tid * 8;

    float v[8];
    f32x4 v0, v1;
    if (c0 <= r) {
        const f32x4* rp = (const f32x4*)row;
        v0 = rp[tid * 2];
        v1 = rp[tid * 2 + 1];
    } else {
        v0 = (f32x4)(-3.0e38f);
        v1 = (f32x4)(-3.0e38f);
    }
    float lmax = -3.0e38f;
#pragma unroll
    for (int k = 0; k < 4; ++k) {
        v[k]     = (c0 + k     <= r) ? v0[k] : -3.0e38f;
        v[k + 4] = (c0 + k + 4 <= r) ? v1[k] : -3.0e38f;
    }
#pragma unroll
    for (int k = 0; k < 8; ++k) lmax = fmaxf(lmax, v[k]);

    __shared__ float red[256];
    red[tid] = lmax; __syncthreads();
    for (int s = 128; s > 0; s >>= 1) {
        if (tid < s) red[tid] = fmaxf(red[tid], red[tid + s]);
        __syncthreads();
    }
    const float m = red[0];
    __syncthreads();

    float lsum = 0.0f;
#pragma unroll
    for (int k = 0; k < 8; ++k) {
        float e = (v[k] > -1.0e38f) ? __expf(v[k] - m) : 0.0f;
        v[k] = e;
        lsum += e;
    }
    red[tid] = lsum; __syncthreads();
    for (int s = 128; s > 0; s >>= 1) {
        if (tid < s) red[tid] += red[tid + s];
        __syncthreads();
    }
    const float inv = 1.0f / red[0];

    if (c0 < cmax) {
        f16x8v o;
#pragma unroll
        for (int k = 0; k < 8; ++k) o[k] = (_Float16)(v[k] * inv);
        ((f16x8v*)prow)[tid] = o;
    }
}

// ---------------------------------------------------------------------------
// layout (R9-verified): x_h[0,16) W2[16,24) Wvt[24,26) Sc[0,64) Q_h[64,80)
// Khl[80,112) Vt[112,128) P[128,160).
// Phase check: projQK reads x_h/W2; projV reads x_h/Wvt; gemm_sc writes
// Sc[0,64) AFTER projV finishes (x_h/W2/Wvt dead) and reads Q_h/Khl;
// softmax reads Sc writes P; gemm_pv reads P/Vt. All disjoint per phase.
// ---------------------------------------------------------------------------
extern "C" void kernel_launch(void* const* d_in, const int* in_sizes, int n_in,
                              void* d_out, int out_size, void* d_ws, size_t ws_size,
                              hipStream_t stream)
{
    constexpr int B = 4, S = 2048, D = 1024;
    constexpr long MB = 1024 * 1024;
    const float* x  = (const float*)d_in[0];
    const float* Wq = (const float*)d_in[1];
    const float* bq = (const float*)d_in[2];
    const float* Wk = (const float*)d_in[3];
    const float* bk = (const float*)d_in[4];
    const float* Wv = (const float*)d_in[5];
    const float* bv = (const float*)d_in[6];
    float* out = (float*)d_out;

    char* ws = (char*)d_ws;
    _Float16* x_h = (_Float16*)(ws + 0);           // [0,16)
    _Float16* W2  = (_Float16*)(ws + 16 * MB);     // [16,24)
    _Float16* Wvt = (_Float16*)(ws + 24 * MB);     // [24,26)
    float*    Sc  = (float*)(ws + 0);              // [0,64) after x/W dead
    _Float16* Q_h = (_Float16*)(ws + 64 * MB);     // [64,80)
    _Float16* Khl = (_Float16*)(ws + 80 * MB);     // [80,112)
    _Float16* Vt  = (_Float16*)(ws + 112 * MB);    // [112,128)
    _Float16* P   = (_Float16*)(ws + 128 * MB);    // [128,160)

    const int M = B * S;
    dim3 blk(256);

    convert_h<<<(M * D / 4 + 255) / 256, blk, 0, stream>>>(x, x_h, (long)M * D / 4);
    transpose_w3<<<dim3(D / 32, D / 32, 3), blk, 0, stream>>>(Wq, Wk, Wv, W2, Wvt, D);
    projQK<<<dim3(256), dim3(512), 0, stream>>>(x_h, W2, Q_h, Khl, bq, bk);
    projV<<<dim3(256), blk, 0, stream>>>(x_h, Wvt, Vt, bv);
    gemm_sc<<<dim3(36, B), dim3(512), 0, stream>>>(Q_h, Khl, Sc);
    softmax_kernel<<<dim3(S, B), blk, 0, stream>>>(Sc, P, S);
    gemm_pv<<<dim3(8, 8, B), blk, 0, stream>>>(P, Vt, out);
}